// Round 26
// baseline (408.592 us; speedup 1.0000x reference)
//
#include <hip/hip_runtime.h>
#include <hip/hip_bf16.h>
#include <math.h>

typedef __bf16 bf16;
typedef __bf16 bf16x4 __attribute__((ext_vector_type(4)));
typedef __bf16 bf16x8 __attribute__((ext_vector_type(8)));
typedef float f32x4 __attribute__((ext_vector_type(4)));
typedef float f32x16 __attribute__((ext_vector_type(16)));
typedef unsigned int u32;
typedef unsigned int u32x4 __attribute__((ext_vector_type(4)));

__device__ __forceinline__ void gload_lds16(const bf16* g, bf16* l) {
  __builtin_amdgcn_global_load_lds(
      (const __attribute__((address_space(1))) void*)g,
      (__attribute__((address_space(3))) void*)l, 16, 0, 0);
}

// pack two f32 -> u32 of two bf16 (lo = a, hi = b)
__device__ __forceinline__ u32 pk2(float a, float b) {
  union { bf16 h; unsigned short u; } x, y;
  x.h = (bf16)a; y.h = (bf16)b;
  return (u32)x.u | ((u32)y.u << 16);
}

#define MF(a, b, c)   __builtin_amdgcn_mfma_f32_16x16x32_bf16((a), (b), (c), 0, 0, 0)
#define MF32(a, b, c) __builtin_amdgcn_mfma_f32_32x32x16_bf16((a), (b), (c), 0, 0, 0)
// fused wait+barrier blocks (opaque: no memory op can cross)
#define VM2_BAR()  asm volatile("s_waitcnt vmcnt(2)\ns_barrier" ::: "memory")
#define VM0_BAR()  asm volatile("s_waitcnt vmcnt(0)\ns_barrier" ::: "memory")

// 128x128 8-wave GEMM (r19/r21-verified skeleton: counted vmcnt, 0-conflict
// chunk-XOR swizzle, double-buffered 64KB LDS -> 2 blocks/CU, per-wave out
// 64x32, supertile group=8 m-inner L2 remap). r26: MFMA shape 16x16x32 ->
// 32x32x16 (2 frags of 32x32 per wave): 2x FLOP/issue-slot, MFMA insts/tile
// 16->8, same ds_reads (12) and acc VGPR (32). A/B lane map: row=l&31,
// k=(l>>5)*8+j (per-shape pattern); C/D: col=lane&31,
// row=(reg&3)+8*(reg>>2)+4*(lane>>5) (HW-verified m74/m101).
// C = A[M,K] @ BT[N,K]^T, bf16 in, fp32 accum.
// EPI 0: bf16 = acc+bias            | 2: bf16 = gelu(acc+bias)
// EPI 4: qkv fused: col<1024 -> (acc+bias)*SCLQ; col in [1024,2048) ->
//        acc+bias; col>=2048 -> acc+bias TRANSPOSED into vt (Cout2).
// EPI 5: bf16 = acc+bias+resf[idx]  (f32 residual -> bf16 out)
// EPI 6: f32  = acc+bias+resh[idx]  (bf16 residual -> f32 out)
template <int EPI>
__global__ __launch_bounds__(512, 4)
void gemmk(const bf16* __restrict__ A, const bf16* __restrict__ BT,
           const float* __restrict__ bias, const void* __restrict__ res,
           void* __restrict__ Cout, void* __restrict__ Cout2,
           int M, int N, int K)
{
  __shared__ alignas(16) bf16 lsA[2][8192];   // [buf][128*64] 16KB each
  __shared__ alignas(16) bf16 lsB[2][8192];

  int nbn = N >> 7;
  int nbm = M >> 7;
  int nwg = nbm * nbn;
  int bid = blockIdx.x;
  int cpx = nwg >> 3;
  int wg  = (bid & 7) * cpx + (bid >> 3);      // XCD swizzle (bijective)
  // supertile remap: groups of 8 n-cols, m-inner (B 2MB stays L2-hot)
  int sg  = wg / (nbm * 8);
  int rem = wg - sg * (nbm * 8);
  int m0 = (rem >> 3) << 7;
  int n0 = (sg * 8 + (rem & 7)) << 7;

  int t = threadIdx.x;
  int l = t & 63, w = t >> 6;
  int gm = w >> 2;               // 0/1: A-half (64 rows) owned by this wave
  int gn = w & 3;                // 0..3: 32-col slice of B
  int l31 = l & 31, l5 = l >> 5, l7 = l & 7;

  int nt = K >> 6;

  const bf16* Ag = A  + (size_t)m0 * K;
  const bf16* Bg = BT + (size_t)n0 * K;

  // frag reads (32x32x16): row = base + (l&31); k = ks*16 + (l>>5)*8
  // -> chunk c = ks*2 + l5; physical chunk = c ^ (row&7) = c ^ l7
  // (bases are multiples of 32). 8 consecutive lanes hit 8 distinct
  // chunks -> conflict-free on the same verified LDS layout.
  int aBase2 = (gm * 64 + l31) << 6;   // + mi*2048
  int bBase2 = (gn * 32 + l31) << 6;

  // staging: each half = 64 rows x 64 = 8KB = 1 chunk/thread (512 thr)
  int srow = t >> 3;
  int g = (t & 7) ^ (srow & 7);        // inverse-swizzled source chunk
  const bf16* sA0 = Ag + (size_t)srow * K + g * 8;
  const bf16* sA1 = Ag + (size_t)(64 + srow) * K + g * 8;
  const bf16* sB0 = Bg + (size_t)srow * K + g * 8;
  const bf16* sB1 = Bg + (size_t)(64 + srow) * K + g * 8;
  int dstE = t * 8;

  f32x16 acc[2];
#pragma unroll
  for (int mi = 0; mi < 2; ++mi)
#pragma unroll
    for (int j = 0; j < 16; ++j) acc[mi][j] = 0.f;

  // prologue: stage tile 0 in order A0,A1,B0,B1 (1 load each)
  gload_lds16(sA0, &lsA[0][dstE]);
  gload_lds16(sA1, &lsA[0][4096 + dstE]);
  gload_lds16(sB0, &lsB[0][dstE]);
  gload_lds16(sB1, &lsB[0][4096 + dstE]);

  bf16x8 af[2][4], bf[4];

  for (int T = 0; T < nt; ++T) {
    int c = T & 1, d = c ^ 1;
    bool st = (T + 1 < nt);
    int k64 = (T + 1) << 6;

    // ---- ph0: A-halves of tile T resident; read A-frags; stage A(T+1)
    VM2_BAR();
#pragma unroll
    for (int mi = 0; mi < 2; ++mi)
#pragma unroll
      for (int ks = 0; ks < 4; ++ks)
        af[mi][ks] = *(const bf16x8*)(&lsA[c][0] + aBase2 + mi * 2048 +
                                      (((ks * 2 + l5) ^ l7) << 3));
    if (st) {
      gload_lds16(sA0 + k64, &lsA[d][dstE]);
      gload_lds16(sA1 + k64, &lsA[d][4096 + dstE]);
    }

    // ---- ph1: B-halves of tile T resident; read B-frags; stage B(T+1);
    //      8 MFMA (32x32x16), ks-outer for dependent-chain spacing
    if (st) VM2_BAR(); else VM0_BAR();
#pragma unroll
    for (int ks = 0; ks < 4; ++ks)
      bf[ks] = *(const bf16x8*)(&lsB[c][0] + bBase2 +
                                (((ks * 2 + l5) ^ l7) << 3));
    if (st) {
      gload_lds16(sB0 + k64, &lsB[d][dstE]);
      gload_lds16(sB1 + k64, &lsB[d][4096 + dstE]);
    }
    __builtin_amdgcn_s_setprio(1);
#pragma unroll
    for (int ks = 0; ks < 4; ++ks)
#pragma unroll
      for (int mi = 0; mi < 2; ++mi)
        acc[mi] = MF32(af[mi][ks], bf[ks], acc[mi]);
    __builtin_amdgcn_s_setprio(0);
  }

  // epilogue: per wave 64 rows x 32 cols; C/D map (HW-verified):
  // col = n0+gn*32+(l&31); row = m0+gm*64+mi*32+(reg&3)+8*(reg>>2)+4*l5
  const float SCLQ = 0.18033688011112042f;   // 0.125 * log2(e)
  bf16* Pb = (bf16*)Cout;
  bf16* Vt = (bf16*)Cout2;
  const float* resf = (const float*)res;
  const bf16* resh = (const bf16*)res;
  int col = n0 + gn * 32 + l31;
  float bv = bias[col];
#pragma unroll
  for (int mi = 0; mi < 2; ++mi) {
    int rowb = m0 + gm * 64 + mi * 32 + l5 * 4;
    if (EPI == 4 && col >= 2048) {
      // V block: write transposed into vt (replaces vtrans kernel)
      int hh = (col >> 6) & 15;
      int dd = col & 63;
#pragma unroll
      for (int reg = 0; reg < 16; ++reg) {
        int row = rowb + (reg & 3) + 8 * (reg >> 2);
        int bb = row >> 11, tok = row & 2047;
        Vt[(size_t)(((bb << 4) + hh) * 64 + dd) * 2048 + tok] =
            (bf16)(acc[mi][reg] + bv);
      }
    } else {
#pragma unroll
      for (int reg = 0; reg < 16; ++reg) {
        int row = rowb + (reg & 3) + 8 * (reg >> 2);
        float v = acc[mi][reg] + bv;
        size_t idx = (size_t)row * N + col;
        if (EPI == 0)      Pb[idx] = (bf16)v;
        else if (EPI == 2) Pb[idx] = (bf16)(0.5f * v * (1.f + erff(v * 0.70710678118654752f)));
        else if (EPI == 4) Pb[idx] = (bf16)((col < 1024) ? v * SCLQ : v);
        else if (EPI == 5) Pb[idx] = (bf16)(v + resf[idx]);
        else if (EPI == 6) ((float*)Cout)[idx] = v + (float)resh[idx];
      }
    }
  }
}

// Horizontally-fused prologue: 4 weight transposes + LN1, one launch.
// blocks [0,12288): transpose-cast tiles; [12288,20480): LN rows.
__global__ __launch_bounds__(256)
void prep(const float* __restrict__ w_attn, bf16* __restrict__ wqkvT,
          const float* __restrict__ w_proj, bf16* __restrict__ wprojT,
          const float* __restrict__ w_fc,   bf16* __restrict__ wfcT,
          const float* __restrict__ w_fc2,  bf16* __restrict__ wfc2T,
          const float* __restrict__ x, const float* __restrict__ ln1w,
          const float* __restrict__ ln1b, bf16* __restrict__ hout)
{
  __shared__ float tile[32][33];
  __shared__ float ps[4], pq[4];
  int id = blockIdx.x;
  int t = threadIdx.x;
  if (id < 12288) {
    const float* W; bf16* WT; int K, N, loc;
    if (id < 3072)      { W = w_attn; WT = wqkvT;  K = 1024; N = 3072; loc = id; }
    else if (id < 4096) { W = w_proj; WT = wprojT; K = 1024; N = 1024; loc = id - 3072; }
    else if (id < 8192) { W = w_fc;   WT = wfcT;   K = 1024; N = 4096; loc = id - 4096; }
    else                { W = w_fc2;  WT = wfc2T;  K = 4096; N = 1024; loc = id - 8192; }
    int nbk = K >> 5;
    int bk = (loc % nbk) * 32, bn = (loc / nbk) * 32;
    int tx = t & 31, ty = t >> 5;
#pragma unroll
    for (int i = ty; i < 32; i += 8)
      tile[i][tx] = W[(size_t)(bk + i) * N + bn + tx];
    __syncthreads();
#pragma unroll
    for (int i = ty; i < 32; i += 8)
      WT[(size_t)(bn + i) * K + bk + tx] = (bf16)tile[tx][i];
  } else {
    int row = id - 12288;
    float4 v = ((const float4*)(x + (size_t)row * 1024))[t];
    float s  = v.x + v.y + v.z + v.w;
    float sq = v.x * v.x + v.y * v.y + v.z * v.z + v.w * v.w;
#pragma unroll
    for (int off = 32; off >= 1; off >>= 1) {
      s  += __shfl_xor(s, off);
      sq += __shfl_xor(sq, off);
    }
    if ((t & 63) == 0) { ps[t >> 6] = s; pq[t >> 6] = sq; }
    __syncthreads();
    s  = ps[0] + ps[1] + ps[2] + ps[3];
    sq = pq[0] + pq[1] + pq[2] + pq[3];
    float mu  = s * (1.f / 1024.f);
    float var = sq * (1.f / 1024.f) - mu * mu;
    float rstd = rsqrtf(var + 1e-5f);
    float4 wv = ((const float4*)ln1w)[t];
    float4 bv = ((const float4*)ln1b)[t];
    size_t o0 = (size_t)row * 1024 + t * 4;
    hout[o0 + 0] = (bf16)((v.x - mu) * rstd * wv.x + bv.x);
    hout[o0 + 1] = (bf16)((v.y - mu) * rstd * wv.y + bv.y);
    hout[o0 + 2] = (bf16)((v.z - mu) * rstd * wv.z + bv.z);
    hout[o0 + 3] = (bf16)((v.w - mu) * rstd * wv.w + bv.w);
  }
}

// LayerNorm, bf16 in -> bf16 out. One block per row (1024).
__global__ __launch_bounds__(256)
void lnh_bf16(const bf16* __restrict__ x, const float* __restrict__ w,
              const float* __restrict__ b, bf16* __restrict__ out)
{
  int row = blockIdx.x;
  int t = threadIdx.x;
  bf16x4 hv = *(const bf16x4*)(x + (size_t)row * 1024 + t * 4);
  float v0 = (float)hv[0], v1 = (float)hv[1], v2 = (float)hv[2], v3 = (float)hv[3];
  float s  = v0 + v1 + v2 + v3;
  float sq = v0 * v0 + v1 * v1 + v2 * v2 + v3 * v3;
#pragma unroll
  for (int off = 32; off >= 1; off >>= 1) {
    s  += __shfl_xor(s, off);
    sq += __shfl_xor(sq, off);
  }
  __shared__ float ps[4], pq[4];
  if ((t & 63) == 0) { ps[t >> 6] = s; pq[t >> 6] = sq; }
  __syncthreads();
  s  = ps[0] + ps[1] + ps[2] + ps[3];
  sq = pq[0] + pq[1] + pq[2] + pq[3];
  float mu  = s * (1.f / 1024.f);
  float var = sq * (1.f / 1024.f) - mu * mu;
  float rstd = rsqrtf(var + 1e-5f);
  float4 wv = ((const float4*)w)[t];
  float4 bv = ((const float4*)b)[t];
  size_t o0 = (size_t)row * 1024 + t * 4;
  out[o0 + 0] = (bf16)((v0 - mu) * rstd * wv.x + bv.x);
  out[o0 + 1] = (bf16)((v1 - mu) * rstd * wv.y + bv.y);
  out[o0 + 2] = (bf16)((v2 - mu) * rstd * wv.z + bv.z);
  out[o0 + 3] = (bf16)((v3 - mu) * rstd * wv.w + bv.w);
}

// Flash causal attention (r18-verified), 8-wave blocks (QBLK=128),
// fixed-cap softmax, swapped QK^T with in-register P-transpose.
__global__ __launch_bounds__(512)
void attn_flash(const bf16* __restrict__ qkv, const bf16* __restrict__ vt,
                bf16* __restrict__ y)
{
  __shared__ alignas(16) bf16 lk[2][4096];
  __shared__ alignas(16) bf16 lv[2][4096];

  int bid = blockIdx.x;
  int bh = bid & 63;
  int qb = 15 - (bid >> 6);            // big q-blocks first
  int b = bh >> 4, h = bh & 15;
  int t = threadIdx.x;
  int w = t >> 6, l = t & 63;
  int lr = l & 15, lg = l >> 4;
  int q0 = qb * 128;
  int qw = q0 + w * 16;
  const size_t RS = 3072;

  const bf16* qbase = qkv + (size_t)(b * 2048) * RS + h * 64;
  const bf16* kbase = qkv + (size_t)(b * 2048) * RS + 1024 + h * 64;
  const bf16* vtb   = vt + (size_t)(bh * 64) * 2048;

  bf16x8 qf[2];
#pragma unroll
  for (int kk = 0; kk < 2; ++kk)
    qf[kk] = *(const bf16x8*)(qbase + (size_t)(qw + lr) * RS + kk * 32 + lg * 8);

  int row = t >> 3, c8 = t & 7;
  int sc8 = c8 ^ (row & 7);
  const bf16* pK = kbase + (size_t)row * RS + sc8 * 8;
  const bf16* pV = vtb + (size_t)row * 2048 + sc8 * 8;
  int dst = t * 8;

  f32x4 zero = {0.f, 0.f, 0.f, 0.f};
  f32x4 o[4];
#pragma unroll
  for (int ni = 0; ni < 4; ++ni) o[ni] = zero;
  float lo = 0.f;                      // denominator partial for q = qw+lr

  int srcA = lr + ((lg & 1) << 5);
  int srcB = srcA + 16;
  int jhalf = lg >> 1;

  int nkb = 2 * qb + 2;
  gload_lds16(pK, &lk[0][dst]);
  gload_lds16(pV, &lv[0][dst]);

  for (int kb = 0; kb < nkb; ++kb) {
    int cur = kb & 1;
    int k0 = kb * 64;
    VM0_BAR();
    if (kb + 1 < nkb) {
      pK += 64 * RS;
      pV += 64;
      gload_lds16(pK, &lk[cur ^ 1][dst]);
      gload_lds16(pV, &lv[cur ^ 1][dst]);
    }
    if (k0 > qw + 15) continue;        // fully masked for this wave (uniform)

    f32x4 s[4];
#pragma unroll
    for (int j = 0; j < 4; ++j) s[j] = zero;
#pragma unroll
    for (int kk = 0; kk < 2; ++kk)
#pragma unroll
      for (int j = 0; j < 4; ++j) {
        int krow = j * 16 + lr;
        bf16x8 kf = *(const bf16x8*)&lk[cur][krow * 64 + (((4 * kk + lg) ^ (krow & 7)) * 8)];
        s[j] = MF(kf, qf[kk], s[j]);   // swapped operands
      }

    bool needmask = (k0 + 63 > qw);    // wave-uniform
    u32 packL[4], packH[4];
#pragma unroll
    for (int j = 0; j < 4; ++j) {
      int kbase_j = k0 + j * 16 + lg * 4;
      int tq = qw + lr;
      float v0 = s[j][0], v1 = s[j][1], v2 = s[j][2], v3 = s[j][3];
      if (needmask) {
        if (kbase_j + 0 > tq) v0 = -1e30f;
        if (kbase_j + 1 > tq) v1 = -1e30f;
        if (kbase_j + 2 > tq) v2 = -1e30f;
        if (kbase_j + 3 > tq) v3 = -1e30f;
      }
      float p0 = exp2f(v0), p1 = exp2f(v1), p2 = exp2f(v2), p3 = exp2f(v3);
      lo += (p0 + p1) + (p2 + p3);
      packL[j] = pk2(p0, p1);
      packH[j] = pk2(p2, p3);
    }

#pragma unroll
    for (int kf = 0; kf < 2; ++kf) {
      u32 la0 = __shfl(packL[2 * kf], srcA), la1 = __shfl(packL[2 * kf + 1], srcA);
      u32 ha0 = __shfl(packH[2 * kf], srcA), ha1 = __shfl(packH[2 * kf + 1], srcA);
      u32 lb0 = __shfl(packL[2 * kf], srcB), lb1 = __shfl(packL[2 * kf + 1], srcB);
      u32 hb0 = __shfl(packH[2 * kf], srcB), hb1 = __shfl(packH[2 * kf + 1], srcB);
      u32x4 pa32;
      pa32[0] = jhalf ? la1 : la0;
      pa32[1] = jhalf ? ha1 : ha0;
      pa32[2] = jhalf ? lb1 : lb0;
      pa32[3] = jhalf ? hb1 : hb0;
      bf16x8 pa = __builtin_bit_cast(bf16x8, pa32);
#pragma unroll
      for (int ni = 0; ni < 4; ++ni) {
        int d = ni * 16 + lr;
        bf16x8 vf = *(const bf16x8*)&lv[cur][d * 64 + (((4 * kf + lg) ^ (d & 7)) * 8)];
        o[ni] = MF(pa, vf, o[ni]);
      }
    }
  }

  lo += __shfl_xor(lo, 16);
  lo += __shfl_xor(lo, 32);
  float inv[4];
#pragma unroll
  for (int r = 0; r < 4; ++r)
    inv[r] = 1.f / __shfl(lo, (lg << 4) | (lg * 4 + r));
#pragma unroll
  for (int ni = 0; ni < 4; ++ni)
#pragma unroll
    for (int r = 0; r < 4; ++r) {
      int tq = qw + lg * 4 + r;
      y[(size_t)(b * 2048 + tq) * 1024 + h * 64 + ni * 16 + lr] = (bf16)(o[ni][r] * inv[r]);
    }
}

extern "C" void kernel_launch(void* const* d_in, const int* in_sizes, int n_in,
                              void* d_out, int out_size, void* d_ws, size_t ws_size,
                              hipStream_t stream) {
  (void)in_sizes; (void)n_in; (void)out_size; (void)ws_size;
  const float* x      = (const float*)d_in[0];
  const float* ln1w   = (const float*)d_in[1];
  const float* ln1b   = (const float*)d_in[2];
  const float* ln2w   = (const float*)d_in[3];
  const float* ln2b   = (const float*)d_in[4];
  const float* w_attn = (const float*)d_in[5];
  const float* b_attn = (const float*)d_in[6];
  const float* w_proj = (const float*)d_in[7];
  const float* b_proj = (const float*)d_in[8];
  const float* w_fc   = (const float*)d_in[9];
  const float* b_fc   = (const float*)d_in[10];
  const float* w_fc2  = (const float*)d_in[11];
  const float* b_fc2  = (const float*)d_in[12];
  float* out = (float*)d_out;

  // workspace: h | [qkv | y] == m | x1h (bf16) | vt | weightsT
  char* p = (char*)d_ws;
  bf16*  h     = (bf16*)p;  p += (size_t)8192 * 1024 * 2;
  bf16*  qkv   = (bf16*)p;
  bf16*  mbuf  = (bf16*)p;  p += (size_t)8192 * 3072 * 2;   // m overlays qkv+y
  bf16*  ybuf  = (bf16*)p;  p += (size_t)8192 * 1024 * 2;
  bf16*  x1h   = (bf16*)p;  p += (size_t)8192 * 1024 * 2;
  bf16*  vt    = (bf16*)p;  p += (size_t)8192 * 2048 * 2;
  bf16*  wqkvT = (bf16*)p;  p += (size_t)3072 * 1024 * 2;
  bf16*  wprojT= (bf16*)p;  p += (size_t)1024 * 1024 * 2;
  bf16*  wfcT  = (bf16*)p;  p += (size_t)4096 * 1024 * 2;
  bf16*  wfc2T = (bf16*)p;  p += (size_t)1024 * 4096 * 2;

  prep<<<20480, 256, 0, stream>>>(w_attn, wqkvT, w_proj, wprojT,
                                  w_fc, wfcT, w_fc2, wfc2T,
                                  x, ln1w, ln1b, h);
  gemmk<4><<<1536, 512, 0, stream>>>(h, wqkvT, b_attn, nullptr, qkv, vt, 8192, 3072, 1024);
  attn_flash<<<1024, 512, 0, stream>>>(qkv, vt, ybuf);
  gemmk<5><<<512, 512, 0, stream>>>(ybuf, wprojT, b_proj, x, x1h, nullptr, 8192, 1024, 1024);
  lnh_bf16<<<8192, 256, 0, stream>>>(x1h, ln2w, ln2b, h);
  gemmk<2><<<2048, 512, 0, stream>>>(h, wfcT, b_fc, nullptr, mbuf, nullptr, 8192, 4096, 1024);
  gemmk<6><<<512, 512, 0, stream>>>(mbuf, wfc2T, b_fc2, x1h, out, nullptr, 8192, 1024, 4096);
}

// Round 27
// 360.240 us; speedup vs baseline: 1.1342x; 1.1342x over previous
//
#include <hip/hip_runtime.h>
#include <hip/hip_bf16.h>
#include <math.h>

typedef __bf16 bf16;
typedef __bf16 bf16x4 __attribute__((ext_vector_type(4)));
typedef __bf16 bf16x8 __attribute__((ext_vector_type(8)));
typedef float f32x4 __attribute__((ext_vector_type(4)));
typedef unsigned int u32;
typedef unsigned int u32x4 __attribute__((ext_vector_type(4)));

__device__ __forceinline__ void gload_lds16(const bf16* g, bf16* l) {
  __builtin_amdgcn_global_load_lds(
      (const __attribute__((address_space(1))) void*)g,
      (__attribute__((address_space(3))) void*)l, 16, 0, 0);
}

// pack two f32 -> u32 of two bf16 (lo = a, hi = b)
__device__ __forceinline__ u32 pk2(float a, float b) {
  union { bf16 h; unsigned short u; } x, y;
  x.h = (bf16)a; y.h = (bf16)b;
  return (u32)x.u | ((u32)y.u << 16);
}

#define MF(a, b, c) __builtin_amdgcn_mfma_f32_16x16x32_bf16((a), (b), (c), 0, 0, 0)
// fused wait+barrier blocks (opaque: no memory op can cross)
#define VM2_BAR()  asm volatile("s_waitcnt vmcnt(2)\ns_barrier" ::: "memory")
#define VM0_BAR()  asm volatile("s_waitcnt vmcnt(0)\ns_barrier" ::: "memory")

// 128x128 8-wave GEMM (r19/r21-verified schedule: counted vmcnt, 0-conflict
// chunk-XOR swizzle, double-buffered 64KB LDS -> 2 blocks/CU, per-wave out
// 64x32, supertile group=8 m-inner L2 remap). [SESSION-VERIFIED OPTIMUM:
// BK=64/2-blk (r15,r24); 16x16x32 MFMA (r26: 32x32 = 4-way LDS conflict);
// schedule frozen (r11/r13/r14/r20 all failed)]
// C = A[M,K] @ BT[N,K]^T, bf16 in, fp32 accum.
// EPI 0: bf16 = acc+bias            | 2: bf16 = gelu(acc+bias)
// EPI 4: qkv fused: col<1024 -> (acc+bias)*SCLQ; col in [1024,2048) ->
//        acc+bias; col>=2048 -> acc+bias TRANSPOSED into vt (Cout2).
// EPI 5: bf16 = acc+bias+resf[idx]  (f32 residual -> bf16 out)
// EPI 6: f32  = acc+bias+resh[idx]  (bf16 residual -> f32 out)
template <int EPI>
__global__ __launch_bounds__(512, 4)
void gemmk(const bf16* __restrict__ A, const bf16* __restrict__ BT,
           const float* __restrict__ bias, const void* __restrict__ res,
           void* __restrict__ Cout, void* __restrict__ Cout2,
           int M, int N, int K)
{
  __shared__ alignas(16) bf16 lsA[2][8192];   // [buf][128*64] 16KB each
  __shared__ alignas(16) bf16 lsB[2][8192];

  int nbn = N >> 7;
  int nbm = M >> 7;
  int nwg = nbm * nbn;
  int bid = blockIdx.x;
  int cpx = nwg >> 3;
  int wg  = (bid & 7) * cpx + (bid >> 3);      // XCD swizzle (bijective)
  // supertile remap: groups of 8 n-cols, m-inner (B 2MB stays L2-hot)
  int sg  = wg / (nbm * 8);
  int rem = wg - sg * (nbm * 8);
  int m0 = (rem >> 3) << 7;
  int n0 = (sg * 8 + (rem & 7)) << 7;

  int t = threadIdx.x;
  int l = t & 63, w = t >> 6;
  int gm = w >> 2;               // 0/1: A-half (64 rows) owned by this wave
  int gn = w & 3;                // 0..3: 32-col slice of B
  int lr = l & 15, lg = l >> 4;

  int nt = K >> 6;

  const bf16* Ag = A  + (size_t)m0 * K;
  const bf16* Bg = BT + (size_t)n0 * K;

  // ds_read element offsets: chunk8 = (kk*4+lg) ^ (row&7); row&7 == lr&7
  int swz0 = (lg ^ (lr & 7)) << 3;
  int swz1 = swz0 ^ 32;
  int aBase = (gm * 64 + lr) << 6;     // + mi*1024
  int bBase = (gn * 32 + lr) << 6;     // + ni*1024

  // staging: each half = 64 rows x 64 = 8KB = 1 chunk/thread (512 thr)
  int srow = t >> 3;
  int g = (t & 7) ^ (srow & 7);        // inverse-swizzled source chunk
  const bf16* sA0 = Ag + (size_t)srow * K + g * 8;
  const bf16* sA1 = Ag + (size_t)(64 + srow) * K + g * 8;
  const bf16* sB0 = Bg + (size_t)srow * K + g * 8;
  const bf16* sB1 = Bg + (size_t)(64 + srow) * K + g * 8;
  int dstE = t * 8;

  f32x4 acc[4][2];
  f32x4 zero = {0.f, 0.f, 0.f, 0.f};
#pragma unroll
  for (int mi = 0; mi < 4; ++mi)
#pragma unroll
    for (int ni = 0; ni < 2; ++ni) acc[mi][ni] = zero;

  // prologue: stage tile 0 in order A0,A1,B0,B1 (1 load each)
  gload_lds16(sA0, &lsA[0][dstE]);
  gload_lds16(sA1, &lsA[0][4096 + dstE]);
  gload_lds16(sB0, &lsB[0][dstE]);
  gload_lds16(sB1, &lsB[0][4096 + dstE]);

  bf16x8 af[4][2], bf[2][2];

  for (int T = 0; T < nt; ++T) {
    int c = T & 1, d = c ^ 1;
    bool st = (T + 1 < nt);
    int k64 = (T + 1) << 6;

    // ---- ph0: A-halves of tile T resident; read A-frags; stage A(T+1)
    VM2_BAR();
#pragma unroll
    for (int mi = 0; mi < 4; ++mi) {
      af[mi][0] = *(const bf16x8*)(&lsA[c][0] + aBase + mi * 1024 + swz0);
      af[mi][1] = *(const bf16x8*)(&lsA[c][0] + aBase + mi * 1024 + swz1);
    }
    if (st) {
      gload_lds16(sA0 + k64, &lsA[d][dstE]);
      gload_lds16(sA1 + k64, &lsA[d][4096 + dstE]);
    }

    // ---- ph1: B-halves of tile T resident; read B-frags; stage B(T+1);
    //      MFMA (consumes A-frags read a phase earlier + B-frags)
    if (st) VM2_BAR(); else VM0_BAR();
#pragma unroll
    for (int ni = 0; ni < 2; ++ni) {
      bf[ni][0] = *(const bf16x8*)(&lsB[c][0] + bBase + ni * 1024 + swz0);
      bf[ni][1] = *(const bf16x8*)(&lsB[c][0] + bBase + ni * 1024 + swz1);
    }
    if (st) {
      gload_lds16(sB0 + k64, &lsB[d][dstE]);
      gload_lds16(sB1 + k64, &lsB[d][4096 + dstE]);
    }
    __builtin_amdgcn_s_setprio(1);
#pragma unroll
    for (int mi = 0; mi < 4; ++mi)
#pragma unroll
      for (int ni = 0; ni < 2; ++ni)
#pragma unroll
        for (int kk = 0; kk < 2; ++kk)
          acc[mi][ni] = MF(af[mi][kk], bf[ni][kk], acc[mi][ni]);
    __builtin_amdgcn_s_setprio(0);
  }

  // epilogue: per wave 64 rows x 32 cols
  const float SCLQ = 0.18033688011112042f;   // 0.125 * log2(e)
  bf16* Pb = (bf16*)Cout;
  bf16* Vt = (bf16*)Cout2;
  const float* resf = (const float*)res;
  const bf16* resh = (const bf16*)res;
#pragma unroll
  for (int mi = 0; mi < 4; ++mi) {
    int row = m0 + gm * 64 + mi * 16 + lg * 4;
#pragma unroll
    for (int ni = 0; ni < 2; ++ni) {
      int col = n0 + gn * 32 + ni * 16 + lr;
      float bv = bias[col];
      f32x4 a = acc[mi][ni];
      if (EPI == 4 && col >= 2048) {
        // V block: write transposed into vt (replaces vtrans kernel)
        int bb = row >> 11, tok = row & 2047;
        int hh = (col >> 6) & 15;
        int dd = col & 63;
        bf16* vp = Vt + (size_t)(((bb << 4) + hh) * 64 + dd) * 2048 + tok;
#pragma unroll
        for (int r = 0; r < 4; ++r) vp[r] = (bf16)(a[r] + bv);
      } else {
#pragma unroll
        for (int r = 0; r < 4; ++r) {
          float v = a[r] + bv;
          size_t idx = (size_t)(row + r) * N + col;
          if (EPI == 0)      Pb[idx] = (bf16)v;
          else if (EPI == 2) Pb[idx] = (bf16)(0.5f * v * (1.f + erff(v * 0.70710678118654752f)));
          else if (EPI == 4) Pb[idx] = (bf16)((col < 1024) ? v * SCLQ : v);
          else if (EPI == 5) Pb[idx] = (bf16)(v + resf[idx]);
          else if (EPI == 6) ((float*)Cout)[idx] = v + (float)resh[idx];
        }
      }
    }
  }
}

// Horizontally-fused prologue: 4 weight transposes + LN1, one launch.
// blocks [0,12288): transpose-cast tiles; [12288,20480): LN rows.
__global__ __launch_bounds__(256)
void prep(const float* __restrict__ w_attn, bf16* __restrict__ wqkvT,
          const float* __restrict__ w_proj, bf16* __restrict__ wprojT,
          const float* __restrict__ w_fc,   bf16* __restrict__ wfcT,
          const float* __restrict__ w_fc2,  bf16* __restrict__ wfc2T,
          const float* __restrict__ x, const float* __restrict__ ln1w,
          const float* __restrict__ ln1b, bf16* __restrict__ hout)
{
  __shared__ float tile[32][33];
  __shared__ float ps[4], pq[4];
  int id = blockIdx.x;
  int t = threadIdx.x;
  if (id < 12288) {
    const float* W; bf16* WT; int K, N, loc;
    if (id < 3072)      { W = w_attn; WT = wqkvT;  K = 1024; N = 3072; loc = id; }
    else if (id < 4096) { W = w_proj; WT = wprojT; K = 1024; N = 1024; loc = id - 3072; }
    else if (id < 8192) { W = w_fc;   WT = wfcT;   K = 1024; N = 4096; loc = id - 4096; }
    else                { W = w_fc2;  WT = wfc2T;  K = 4096; N = 1024; loc = id - 8192; }
    int nbk = K >> 5;
    int bk = (loc % nbk) * 32, bn = (loc / nbk) * 32;
    int tx = t & 31, ty = t >> 5;
#pragma unroll
    for (int i = ty; i < 32; i += 8)
      tile[i][tx] = W[(size_t)(bk + i) * N + bn + tx];
    __syncthreads();
#pragma unroll
    for (int i = ty; i < 32; i += 8)
      WT[(size_t)(bn + i) * K + bk + tx] = (bf16)tile[tx][i];
  } else {
    int row = id - 12288;
    float4 v = ((const float4*)(x + (size_t)row * 1024))[t];
    float s  = v.x + v.y + v.z + v.w;
    float sq = v.x * v.x + v.y * v.y + v.z * v.z + v.w * v.w;
#pragma unroll
    for (int off = 32; off >= 1; off >>= 1) {
      s  += __shfl_xor(s, off);
      sq += __shfl_xor(sq, off);
    }
    if ((t & 63) == 0) { ps[t >> 6] = s; pq[t >> 6] = sq; }
    __syncthreads();
    s  = ps[0] + ps[1] + ps[2] + ps[3];
    sq = pq[0] + pq[1] + pq[2] + pq[3];
    float mu  = s * (1.f / 1024.f);
    float var = sq * (1.f / 1024.f) - mu * mu;
    float rstd = rsqrtf(var + 1e-5f);
    float4 wv = ((const float4*)ln1w)[t];
    float4 bv = ((const float4*)ln1b)[t];
    size_t o0 = (size_t)row * 1024 + t * 4;
    hout[o0 + 0] = (bf16)((v.x - mu) * rstd * wv.x + bv.x);
    hout[o0 + 1] = (bf16)((v.y - mu) * rstd * wv.y + bv.y);
    hout[o0 + 2] = (bf16)((v.z - mu) * rstd * wv.z + bv.z);
    hout[o0 + 3] = (bf16)((v.w - mu) * rstd * wv.w + bv.w);
  }
}

// LayerNorm, bf16 in -> bf16 out. One block per row (1024).
__global__ __launch_bounds__(256)
void lnh_bf16(const bf16* __restrict__ x, const float* __restrict__ w,
              const float* __restrict__ b, bf16* __restrict__ out)
{
  int row = blockIdx.x;
  int t = threadIdx.x;
  bf16x4 hv = *(const bf16x4*)(x + (size_t)row * 1024 + t * 4);
  float v0 = (float)hv[0], v1 = (float)hv[1], v2 = (float)hv[2], v3 = (float)hv[3];
  float s  = v0 + v1 + v2 + v3;
  float sq = v0 * v0 + v1 * v1 + v2 * v2 + v3 * v3;
#pragma unroll
  for (int off = 32; off >= 1; off >>= 1) {
    s  += __shfl_xor(s, off);
    sq += __shfl_xor(sq, off);
  }
  __shared__ float ps[4], pq[4];
  if ((t & 63) == 0) { ps[t >> 6] = s; pq[t >> 6] = sq; }
  __syncthreads();
  s  = ps[0] + ps[1] + ps[2] + ps[3];
  sq = pq[0] + pq[1] + pq[2] + pq[3];
  float mu  = s * (1.f / 1024.f);
  float var = sq * (1.f / 1024.f) - mu * mu;
  float rstd = rsqrtf(var + 1e-5f);
  float4 wv = ((const float4*)w)[t];
  float4 bv = ((const float4*)b)[t];
  size_t o0 = (size_t)row * 1024 + t * 4;
  out[o0 + 0] = (bf16)((v0 - mu) * rstd * wv.x + bv.x);
  out[o0 + 1] = (bf16)((v1 - mu) * rstd * wv.y + bv.y);
  out[o0 + 2] = (bf16)((v2 - mu) * rstd * wv.z + bv.z);
  out[o0 + 3] = (bf16)((v3 - mu) * rstd * wv.w + bv.w);
}

// Flash causal attention (r18-verified), 8-wave blocks (QBLK=128),
// fixed-cap softmax, swapped QK^T with in-register P-transpose.
__global__ __launch_bounds__(512)
void attn_flash(const bf16* __restrict__ qkv, const bf16* __restrict__ vt,
                bf16* __restrict__ y)
{
  __shared__ alignas(16) bf16 lk[2][4096];
  __shared__ alignas(16) bf16 lv[2][4096];

  int bid = blockIdx.x;
  int bh = bid & 63;
  int qb = 15 - (bid >> 6);            // big q-blocks first
  int b = bh >> 4, h = bh & 15;
  int t = threadIdx.x;
  int w = t >> 6, l = t & 63;
  int lr = l & 15, lg = l >> 4;
  int q0 = qb * 128;
  int qw = q0 + w * 16;
  const size_t RS = 3072;

  const bf16* qbase = qkv + (size_t)(b * 2048) * RS + h * 64;
  const bf16* kbase = qkv + (size_t)(b * 2048) * RS + 1024 + h * 64;
  const bf16* vtb   = vt + (size_t)(bh * 64) * 2048;

  bf16x8 qf[2];
#pragma unroll
  for (int kk = 0; kk < 2; ++kk)
    qf[kk] = *(const bf16x8*)(qbase + (size_t)(qw + lr) * RS + kk * 32 + lg * 8);

  int row = t >> 3, c8 = t & 7;
  int sc8 = c8 ^ (row & 7);
  const bf16* pK = kbase + (size_t)row * RS + sc8 * 8;
  const bf16* pV = vtb + (size_t)row * 2048 + sc8 * 8;
  int dst = t * 8;

  f32x4 zero = {0.f, 0.f, 0.f, 0.f};
  f32x4 o[4];
#pragma unroll
  for (int ni = 0; ni < 4; ++ni) o[ni] = zero;
  float lo = 0.f;                      // denominator partial for q = qw+lr

  int srcA = lr + ((lg & 1) << 5);
  int srcB = srcA + 16;
  int jhalf = lg >> 1;

  int nkb = 2 * qb + 2;
  gload_lds16(pK, &lk[0][dst]);
  gload_lds16(pV, &lv[0][dst]);

  for (int kb = 0; kb < nkb; ++kb) {
    int cur = kb & 1;
    int k0 = kb * 64;
    VM0_BAR();
    if (kb + 1 < nkb) {
      pK += 64 * RS;
      pV += 64;
      gload_lds16(pK, &lk[cur ^ 1][dst]);
      gload_lds16(pV, &lv[cur ^ 1][dst]);
    }
    if (k0 > qw + 15) continue;        // fully masked for this wave (uniform)

    f32x4 s[4];
#pragma unroll
    for (int j = 0; j < 4; ++j) s[j] = zero;
#pragma unroll
    for (int kk = 0; kk < 2; ++kk)
#pragma unroll
      for (int j = 0; j < 4; ++j) {
        int krow = j * 16 + lr;
        bf16x8 kf = *(const bf16x8*)&lk[cur][krow * 64 + (((4 * kk + lg) ^ (krow & 7)) * 8)];
        s[j] = MF(kf, qf[kk], s[j]);   // swapped operands
      }

    bool needmask = (k0 + 63 > qw);    // wave-uniform
    u32 packL[4], packH[4];
#pragma unroll
    for (int j = 0; j < 4; ++j) {
      int kbase_j = k0 + j * 16 + lg * 4;
      int tq = qw + lr;
      float v0 = s[j][0], v1 = s[j][1], v2 = s[j][2], v3 = s[j][3];
      if (needmask) {
        if (kbase_j + 0 > tq) v0 = -1e30f;
        if (kbase_j + 1 > tq) v1 = -1e30f;
        if (kbase_j + 2 > tq) v2 = -1e30f;
        if (kbase_j + 3 > tq) v3 = -1e30f;
      }
      float p0 = exp2f(v0), p1 = exp2f(v1), p2 = exp2f(v2), p3 = exp2f(v3);
      lo += (p0 + p1) + (p2 + p3);
      packL[j] = pk2(p0, p1);
      packH[j] = pk2(p2, p3);
    }

#pragma unroll
    for (int kf = 0; kf < 2; ++kf) {
      u32 la0 = __shfl(packL[2 * kf], srcA), la1 = __shfl(packL[2 * kf + 1], srcA);
      u32 ha0 = __shfl(packH[2 * kf], srcA), ha1 = __shfl(packH[2 * kf + 1], srcA);
      u32 lb0 = __shfl(packL[2 * kf], srcB), lb1 = __shfl(packL[2 * kf + 1], srcB);
      u32 hb0 = __shfl(packH[2 * kf], srcB), hb1 = __shfl(packH[2 * kf + 1], srcB);
      u32x4 pa32;
      pa32[0] = jhalf ? la1 : la0;
      pa32[1] = jhalf ? ha1 : ha0;
      pa32[2] = jhalf ? lb1 : lb0;
      pa32[3] = jhalf ? hb1 : hb0;
      bf16x8 pa = __builtin_bit_cast(bf16x8, pa32);
#pragma unroll
      for (int ni = 0; ni < 4; ++ni) {
        int d = ni * 16 + lr;
        bf16x8 vf = *(const bf16x8*)&lv[cur][d * 64 + (((4 * kf + lg) ^ (d & 7)) * 8)];
        o[ni] = MF(pa, vf, o[ni]);
      }
    }
  }

  lo += __shfl_xor(lo, 16);
  lo += __shfl_xor(lo, 32);
  float inv[4];
#pragma unroll
  for (int r = 0; r < 4; ++r)
    inv[r] = 1.f / __shfl(lo, (lg << 4) | (lg * 4 + r));
#pragma unroll
  for (int ni = 0; ni < 4; ++ni)
#pragma unroll
    for (int r = 0; r < 4; ++r) {
      int tq = qw + lg * 4 + r;
      y[(size_t)(b * 2048 + tq) * 1024 + h * 64 + ni * 16 + lr] = (bf16)(o[ni][r] * inv[r]);
    }
}

extern "C" void kernel_launch(void* const* d_in, const int* in_sizes, int n_in,
                              void* d_out, int out_size, void* d_ws, size_t ws_size,
                              hipStream_t stream) {
  (void)in_sizes; (void)n_in; (void)out_size; (void)ws_size;
  const float* x      = (const float*)d_in[0];
  const float* ln1w   = (const float*)d_in[1];
  const float* ln1b   = (const float*)d_in[2];
  const float* ln2w   = (const float*)d_in[3];
  const float* ln2b   = (const float*)d_in[4];
  const float* w_attn = (const float*)d_in[5];
  const float* b_attn = (const float*)d_in[6];
  const float* w_proj = (const float*)d_in[7];
  const float* b_proj = (const float*)d_in[8];
  const float* w_fc   = (const float*)d_in[9];
  const float* b_fc   = (const float*)d_in[10];
  const float* w_fc2  = (const float*)d_in[11];
  const float* b_fc2  = (const float*)d_in[12];
  float* out = (float*)d_out;

  // workspace: h | [qkv | y] == m | x1h (bf16) | vt | weightsT
  char* p = (char*)d_ws;
  bf16*  h     = (bf16*)p;  p += (size_t)8192 * 1024 * 2;
  bf16*  qkv   = (bf16*)p;
  bf16*  mbuf  = (bf16*)p;  p += (size_t)8192 * 3072 * 2;   // m overlays qkv+y
  bf16*  ybuf  = (bf16*)p;  p += (size_t)8192 * 1024 * 2;
  bf16*  x1h   = (bf16*)p;  p += (size_t)8192 * 1024 * 2;
  bf16*  vt    = (bf16*)p;  p += (size_t)8192 * 2048 * 2;
  bf16*  wqkvT = (bf16*)p;  p += (size_t)3072 * 1024 * 2;
  bf16*  wprojT= (bf16*)p;  p += (size_t)1024 * 1024 * 2;
  bf16*  wfcT  = (bf16*)p;  p += (size_t)4096 * 1024 * 2;
  bf16*  wfc2T = (bf16*)p;  p += (size_t)1024 * 4096 * 2;

  prep<<<20480, 256, 0, stream>>>(w_attn, wqkvT, w_proj, wprojT,
                                  w_fc, wfcT, w_fc2, wfc2T,
                                  x, ln1w, ln1b, h);
  gemmk<4><<<1536, 512, 0, stream>>>(h, wqkvT, b_attn, nullptr, qkv, vt, 8192, 3072, 1024);
  attn_flash<<<1024, 512, 0, stream>>>(qkv, vt, ybuf);
  gemmk<5><<<512, 512, 0, stream>>>(ybuf, wprojT, b_proj, x, x1h, nullptr, 8192, 1024, 1024);
  lnh_bf16<<<8192, 256, 0, stream>>>(x1h, ln2w, ln2b, h);
  gemmk<2><<<2048, 512, 0, stream>>>(h, wfcT, b_fc, nullptr, mbuf, nullptr, 8192, 4096, 1024);
  gemmk<6><<<512, 512, 0, stream>>>(mbuf, wfc2T, b_fc2, x1h, out, nullptr, 8192, 1024, 4096);
}